// Round 1
// baseline (83.183 us; speedup 1.0000x reference)
//
#include <hip/hip_runtime.h>
#include <math.h>

#define BB 8
#define HH 16
#define NN 1024
#define TB 256
#define POWN 4          // own points per thread (block owns all 1024)
#define NSC 4           // scan chunks per bh
#define SCH 256         // scan points per block (NN / NSC)

// ws layout (floats): partial row-mins
//   part[(bh*NSC + sc)*NN + i] = min over scan-chunk sc of key(i, j)  (+ own_sq)
// 128*4*1024 = 524288 floats = 2 MB. Every slot written exactly once.

// ---------------------------------------------------------------------------
// chamfer: ONLY pass A is computed. By the reflection-isometry identity,
//   sum_j min_i d2[i,j] == sum_i min_j d2[i,j],  so sde = 2*mean_i min_j d2.
// Block (bh, sc): own = ALL 1024 reflected points (POWN=4/thread, coords
// pre-scaled by -2), scan = raw samples [sc*256, +256) in LDS as
// float4{x,y,z,sq}. Inner: key = fma(mx,qx, fma(my,qy, fma(mz,qz, q.sq))),
// 4-deep unroll with EXPLICIT register double-buffer prefetch (next 4
// broadcast ds_read_b128 issued before current group's FMA chains), and
// min3-friendly paired accumulators (fminf(fminf(m,da),db) -> v_min3_f32).
// Writes per-own-point partials (coalesced), no atomics, no ws init.
// ---------------------------------------------------------------------------
__global__ __launch_bounds__(TB) void chamfer_kernel(
    const float* __restrict__ y_pred,
    const float* __restrict__ sp,
    float* __restrict__ ws)
{
    __shared__ __align__(16) float4 pts[SCH];   // 4 KB

    const int blk = blockIdx.x;
    const int bh  = blk >> 2;            // / NSC
    const int sc  = blk & (NSC - 1);
    const int b   = bh >> 4;             // HH = 16
    const int tid = threadIdx.x;

    float pnx = y_pred[bh * 4 + 0];
    float pny = y_pred[bh * 4 + 1];
    float pnz = y_pred[bh * 4 + 2];
    float pd  = y_pred[bh * 4 + 3];
    float inv = 1.0f / sqrtf(pnx * pnx + pny * pny + pnz * pnz);
    pnx *= inv; pny *= inv; pnz *= inv;

    const float* spb = sp + (size_t)b * NN * 3;

    // stage scan chunk: raw samples with squared norm (1 point / thread)
    {
        int j = sc * SCH + tid;
        float x = spb[j * 3 + 0], y = spb[j * 3 + 1], z = spb[j * 3 + 2];
        pts[tid] = make_float4(x, y, z, x * x + y * y + z * z);
    }

    // own points: reflected, pre-scaled by -2
    float mx[POWN], my[POWN], mz[POWN], osq[POWN];
#pragma unroll
    for (int u = 0; u < POWN; ++u) {
        int i = u * TB + tid;
        float x = spb[i * 3 + 0], y = spb[i * 3 + 1], z = spb[i * 3 + 2];
        float proj = x * pnx + y * pny + z * pnz + pd;
        x -= 2.0f * proj * pnx;
        y -= 2.0f * proj * pny;
        z -= 2.0f * proj * pnz;
        osq[u] = x * x + y * y + z * z;
        mx[u] = -2.0f * x; my[u] = -2.0f * y; mz[u] = -2.0f * z;
    }
    __syncthreads();

    float m0[POWN], m1[POWN];
#pragma unroll
    for (int u = 0; u < POWN; ++u) { m0[u] = 3.4e38f; m1[u] = 3.4e38f; }

#define DIST(q, u) fmaf(mx[u], q.x, fmaf(my[u], q.y, fmaf(mz[u], q.z, q.w)))
#define STEP4 do { \
    _Pragma("unroll") \
    for (int u = 0; u < POWN; ++u) { \
        float da = DIST(qa, u); \
        float db = DIST(qb, u); \
        float dc = DIST(qc, u); \
        float dd = DIST(qd, u); \
        m0[u] = fminf(fminf(m0[u], da), db); \
        m1[u] = fminf(fminf(m1[u], dc), dd); \
    } } while (0)

    float4 qa = pts[0], qb = pts[1], qc = pts[2], qd = pts[3];
    for (int j = 0; j < SCH - 4; j += 4) {
        // prefetch next group while current group's FMAs run
        float4 na = pts[j + 4];
        float4 nb = pts[j + 5];
        float4 nc = pts[j + 6];
        float4 nd = pts[j + 7];
        STEP4;
        qa = na; qb = nb; qc = nc; qd = nd;
    }
    STEP4;   // last group (pts[SCH-4 .. SCH-1])

#undef STEP4
#undef DIST

    float* wp = ws + (size_t)(bh * NSC + sc) * NN;
#pragma unroll
    for (int u = 0; u < POWN; ++u)
        wp[u * TB + tid] = osq[u] + fminf(m0[u], m1[u]);
}

// ---------------------------------------------------------------------------
// finalize (per batch, 256 threads): centroid; sde[h] = 2/N * sum_i
// min over NSC partials; conf; angle-NMS; stable rank; write.
// Partial-min reduction is float4-vectorized (64 x 16B loads / thread).
// ---------------------------------------------------------------------------
__global__ __launch_bounds__(TB) void finalize_kernel(
    const float* __restrict__ ws,
    const float* __restrict__ y_pred,
    const float* __restrict__ sp,
    float* __restrict__ out)
{
    const int b   = blockIdx.x;
    const int tid = threadIdx.x;

    __shared__ float sde_s[HH], nx_s[HH], ny_s[HH], nz_s[HH], d_s[HH], conf_s[HH];
    __shared__ float cmacc[3];
    __shared__ int keep_s[HH];

    if (tid < HH) sde_s[tid] = 0.0f;
    if (tid < 3)  cmacc[tid] = 0.0f;
    __syncthreads();

    // centroid: 1024 samples over 256 threads
    const float* spb = sp + (size_t)b * NN * 3;
    float sx = 0.0f, sy = 0.0f, sz = 0.0f;
    for (int p = tid; p < NN; p += TB) {
        sx += spb[p * 3 + 0];
        sy += spb[p * 3 + 1];
        sz += spb[p * 3 + 2];
    }
    for (int off = 32; off; off >>= 1) {
        sx += __shfl_down(sx, off, 64);
        sy += __shfl_down(sy, off, 64);
        sz += __shfl_down(sz, off, 64);
    }
    if ((tid & 63) == 0) {
        atomicAdd(&cmacc[0], sx);
        atomicAdd(&cmacc[1], sy);
        atomicAdd(&cmacc[2], sz);
    }

    // sde accumulation: 16 threads per h, float4 over i, min over NSC chunks
    {
        const int h   = tid >> 4;
        const int sub = tid & 15;
        const float* base = ws + (size_t)((b * HH + h) * NSC) * NN;
        const float4* q0 = (const float4*)(base);
        const float4* q1 = (const float4*)(base + NN);
        const float4* q2 = (const float4*)(base + 2 * NN);
        const float4* q3 = (const float4*)(base + 3 * NN);
        float acc = 0.0f;
        for (int g = 0; g < 16; ++g) {
            int i4 = sub * 16 + g;
            float4 a0 = q0[i4], a1 = q1[i4], a2 = q2[i4], a3 = q3[i4];
            float e0 = fminf(fminf(a0.x, a1.x), fminf(a2.x, a3.x));
            float e1 = fminf(fminf(a0.y, a1.y), fminf(a2.y, a3.y));
            float e2 = fminf(fminf(a0.z, a1.z), fminf(a2.z, a3.z));
            float e3 = fminf(fminf(a0.w, a1.w), fminf(a2.w, a3.w));
            acc += (e0 + e1) + (e2 + e3);
        }
        atomicAdd(&sde_s[h], acc);
    }
    __syncthreads();

    const float cmx = cmacc[0] / NN, cmy = cmacc[1] / NN, cmz = cmacc[2] / NN;

    if (tid < HH) {
        int h = tid;
        float nx = y_pred[(b * HH + h) * 4 + 0];
        float ny = y_pred[(b * HH + h) * 4 + 1];
        float nz = y_pred[(b * HH + h) * 4 + 2];
        float d  = y_pred[(b * HH + h) * 4 + 3];
        float inv = 1.0f / sqrtf(nx * nx + ny * ny + nz * nz);
        nx *= inv; ny *= inv; nz *= inv;
        nx_s[h] = nx; ny_s[h] = ny; nz_s[h] = nz; d_s[h] = d;
        sde_s[h] = sde_s[h] * (2.0f / NN);     // both chamfer terms are equal
    }
    __syncthreads();

    if (tid < HH) {
        int h = tid;
        float mn = sde_s[0], mx = sde_s[0];
        for (int g = 1; g < HH; ++g) {
            mn = fminf(mn, sde_s[g]);
            mx = fmaxf(mx, sde_s[g]);
        }
        float sde  = sde_s[h];
        float conf = 1.0f - (sde - mn) / fabsf(mx - mn);
        conf_s[h]  = conf;
        bool valid = (sde <= 10.0f);
        bool sup   = false;
        if (valid) {
            for (int g = 0; g < HH; ++g) {
                if (g == h) continue;
                float c = nx_s[h] * nx_s[g] + ny_s[h] * ny_s[g] + nz_s[h] * nz_s[g];
                c = fminf(1.0f, fmaxf(-1.0f, c));
                float ang = acosf(c) * 57.29577951308232f;
                bool close = (ang < 30.0f) || (180.0f - ang < 30.0f);
                if (close && (sde_s[g] <= 10.0f) && (sde >= sde_s[g])) sup = true;
            }
        }
        keep_s[h] = (valid && !sup) ? 1 : 0;
    }
    __syncthreads();

    if (tid < HH) {
        int h = tid;
        // stable descending rank on key = keep ? conf : -inf (jnp.argsort(-key))
        float keyh = keep_s[h] ? conf_s[h] : -INFINITY;
        int pos = 0;
        for (int g = 0; g < HH; ++g) {
            float keyg = keep_s[g] ? conf_s[g] : -INFINITY;
            if (keyg > keyh || (keyg == keyh && g < h)) ++pos;
        }
        float nx = nx_s[h], ny = ny_s[h], nz = nz_s[h];
        float t  = nx * cmx + ny * cmy + nz * cmz + d_s[h];
        float px = cmx - t * nx, py = cmy - t * ny, pz = cmz - t * nz;

        float* o = out + (size_t)(b * HH + pos) * 8;
        if (keep_s[h]) {
            o[0] = nx; o[1] = ny; o[2] = nz;
            o[3] = px; o[4] = py; o[5] = pz;
            o[6] = conf_s[h];
            o[7] = sde_s[h];
        } else {
            for (int c = 0; c < 8; ++c) o[c] = 0.0f;
        }
    }
}

extern "C" void kernel_launch(void* const* d_in, const int* in_sizes, int n_in,
                              void* d_out, int out_size, void* d_ws, size_t ws_size,
                              hipStream_t stream) {
    const float* y_pred = (const float*)d_in[0];   // (8,16,4) f32
    const float* sp     = (const float*)d_in[1];   // (8,1024,3) f32
    float* out          = (float*)d_out;           // (8,16,8) f32
    float* ws           = (float*)d_ws;            // 2 MB partials, all written

    chamfer_kernel<<<dim3(BB * HH * NSC), dim3(TB), 0, stream>>>(y_pred, sp, ws);
    finalize_kernel<<<dim3(BB), dim3(TB), 0, stream>>>(ws, y_pred, sp, out);
}

// Round 2
// 78.538 us; speedup vs baseline: 1.0591x; 1.0591x over previous
//
#include <hip/hip_runtime.h>
#include <math.h>

#define BB 8
#define HH 16
#define NN 1024
#define TB 256

// ws layout (floats): ws[bh*4 + q] = sum over own-quarter q's 256 points of
// full min_j d2(reflected_i, sp_j). 128*4 = 512 floats. Written once, plain
// stores, no atomics, no init required.

// ---------------------------------------------------------------------------
// chamfer: ONLY pass A is computed. By the reflection-isometry identity,
//   sum_j min_i d2[i,j] == sum_i min_j d2[i,j],  so sde = 2*mean_i min_j d2.
// Block (bh, q): own = reflected points [q*256, +256) (1/thread, coords
// pre-scaled by -2), scan = ALL 1024 raw samples in LDS as float4{x,y,z,sq}.
// Because the block scans every j, min_j completes in-block, so the i-sum
// reduces to ONE float per block (shfl tree + 4-wave LDS combine, fixed
// order, deterministic). Kills the old 1-2 MB partials round-trip and the
// latency-bound finalize reduction entirely.
// Inner: key = fma(mx,qx, fma(my,qy, fma(mz,qz, q.sq))), unroll 8, paired
// accumulators so fminf(fminf(m,da),db) folds to v_min3_f32. No manual
// register rotation (round-1 lesson: the compiler's counted lgkmcnt
// pipelining beats explicit prefetch + 32 v_movs/group).
// ---------------------------------------------------------------------------
__global__ __launch_bounds__(TB) void chamfer_kernel(
    const float* __restrict__ y_pred,
    const float* __restrict__ sp,
    float* __restrict__ ws)
{
    __shared__ __align__(16) float4 pts[NN];   // 16 KB
    __shared__ float wsum[4];

    const int blk = blockIdx.x;          // 512 blocks
    const int bh  = blk >> 2;
    const int q   = blk & 3;
    const int b   = bh >> 4;             // HH = 16
    const int tid = threadIdx.x;

    float pnx = y_pred[bh * 4 + 0];
    float pny = y_pred[bh * 4 + 1];
    float pnz = y_pred[bh * 4 + 2];
    float pd  = y_pred[bh * 4 + 3];
    float inv = 1.0f / sqrtf(pnx * pnx + pny * pny + pnz * pnz);
    pnx *= inv; pny *= inv; pnz *= inv;

    const float* spb = sp + (size_t)b * NN * 3;

    // stage ALL scan points with squared norm (4 per thread; sp is 96 KB
    // total and read by all blocks -> L2-resident)
    for (int k = tid; k < NN; k += TB) {
        float x = spb[k * 3 + 0], y = spb[k * 3 + 1], z = spb[k * 3 + 2];
        pts[k] = make_float4(x, y, z, x * x + y * y + z * z);
    }

    // own point: reflected, pre-scaled by -2
    float mx, my, mz, osq;
    {
        int i = q * TB + tid;
        float x = spb[i * 3 + 0], y = spb[i * 3 + 1], z = spb[i * 3 + 2];
        float proj = x * pnx + y * pny + z * pnz + pd;
        x -= 2.0f * proj * pnx;
        y -= 2.0f * proj * pny;
        z -= 2.0f * proj * pnz;
        osq = x * x + y * y + z * z;
        mx = -2.0f * x; my = -2.0f * y; mz = -2.0f * z;
    }
    __syncthreads();

    float m0 = 3.4e38f, m1 = 3.4e38f;

#define DIST(qq) fmaf(mx, qq.x, fmaf(my, qq.y, fmaf(mz, qq.z, qq.w)))
    for (int j = 0; j < NN; j += 8) {
        float4 q0 = pts[j + 0];
        float4 q1 = pts[j + 1];
        float4 q2 = pts[j + 2];
        float4 q3 = pts[j + 3];
        float4 q4 = pts[j + 4];
        float4 q5 = pts[j + 5];
        float4 q6 = pts[j + 6];
        float4 q7 = pts[j + 7];
        float d0 = DIST(q0), d1 = DIST(q1), d2 = DIST(q2), d3 = DIST(q3);
        float d4 = DIST(q4), d5 = DIST(q5), d6 = DIST(q6), d7 = DIST(q7);
        m0 = fminf(fminf(m0, d0), d1);     // v_min3_f32
        m1 = fminf(fminf(m1, d2), d3);
        m0 = fminf(fminf(m0, d4), d5);
        m1 = fminf(fminf(m1, d6), d7);
    }
#undef DIST

    float dmin = osq + fminf(m0, m1);      // complete min_j d2 for own i

    // in-block sum over 256 own points (deterministic: shfl tree + indexed
    // 4-wave combine by thread 0)
    float s = dmin;
    for (int off = 32; off; off >>= 1) s += __shfl_down(s, off, 64);
    if ((tid & 63) == 0) wsum[tid >> 6] = s;
    __syncthreads();
    if (tid == 0)
        ws[bh * 4 + q] = (wsum[0] + wsum[1]) + (wsum[2] + wsum[3]);
}

// ---------------------------------------------------------------------------
// finalize (per batch, 256 threads): centroid; sde[h] = 2/N * (4 block sums
// in fixed order); conf; angle-NMS; stable rank; write. The heavy partials
// reduction is gone -- reads 64 floats per batch, L2-hot.
// ---------------------------------------------------------------------------
__global__ __launch_bounds__(TB) void finalize_kernel(
    const float* __restrict__ ws,
    const float* __restrict__ y_pred,
    const float* __restrict__ sp,
    float* __restrict__ out)
{
    const int b   = blockIdx.x;
    const int tid = threadIdx.x;

    __shared__ float sde_s[HH], nx_s[HH], ny_s[HH], nz_s[HH], d_s[HH], conf_s[HH];
    __shared__ float cmacc[3];
    __shared__ int keep_s[HH];

    if (tid < 3) cmacc[tid] = 0.0f;
    __syncthreads();

    // centroid: 1024 samples over 256 threads
    const float* spb = sp + (size_t)b * NN * 3;
    float sx = 0.0f, sy = 0.0f, sz = 0.0f;
    for (int p = tid; p < NN; p += TB) {
        sx += spb[p * 3 + 0];
        sy += spb[p * 3 + 1];
        sz += spb[p * 3 + 2];
    }
    for (int off = 32; off; off >>= 1) {
        sx += __shfl_down(sx, off, 64);
        sy += __shfl_down(sy, off, 64);
        sz += __shfl_down(sz, off, 64);
    }
    if ((tid & 63) == 0) {
        atomicAdd(&cmacc[0], sx);
        atomicAdd(&cmacc[1], sy);
        atomicAdd(&cmacc[2], sz);
    }
    __syncthreads();

    const float cmx = cmacc[0] / NN, cmy = cmacc[1] / NN, cmz = cmacc[2] / NN;

    if (tid < HH) {
        int h = tid;
        float nx = y_pred[(b * HH + h) * 4 + 0];
        float ny = y_pred[(b * HH + h) * 4 + 1];
        float nz = y_pred[(b * HH + h) * 4 + 2];
        float d  = y_pred[(b * HH + h) * 4 + 3];
        float inv = 1.0f / sqrtf(nx * nx + ny * ny + nz * nz);
        nx *= inv; ny *= inv; nz *= inv;
        nx_s[h] = nx; ny_s[h] = ny; nz_s[h] = nz; d_s[h] = d;
        const float* w = ws + (size_t)(b * HH + h) * 4;
        // fixed-order sum of the 4 block partials, both chamfer terms equal
        sde_s[h] = ((w[0] + w[1]) + (w[2] + w[3])) * (2.0f / NN);
    }
    __syncthreads();

    if (tid < HH) {
        int h = tid;
        float mn = sde_s[0], mx = sde_s[0];
        for (int g = 1; g < HH; ++g) {
            mn = fminf(mn, sde_s[g]);
            mx = fmaxf(mx, sde_s[g]);
        }
        float sde  = sde_s[h];
        float conf = 1.0f - (sde - mn) / fabsf(mx - mn);
        conf_s[h]  = conf;
        bool valid = (sde <= 10.0f);
        bool sup   = false;
        if (valid) {
            for (int g = 0; g < HH; ++g) {
                if (g == h) continue;
                float c = nx_s[h] * nx_s[g] + ny_s[h] * ny_s[g] + nz_s[h] * nz_s[g];
                c = fminf(1.0f, fmaxf(-1.0f, c));
                float ang = acosf(c) * 57.29577951308232f;
                bool close = (ang < 30.0f) || (180.0f - ang < 30.0f);
                if (close && (sde_s[g] <= 10.0f) && (sde >= sde_s[g])) sup = true;
            }
        }
        keep_s[h] = (valid && !sup) ? 1 : 0;
    }
    __syncthreads();

    if (tid < HH) {
        int h = tid;
        // stable descending rank on key = keep ? conf : -inf (jnp.argsort(-key))
        float keyh = keep_s[h] ? conf_s[h] : -INFINITY;
        int pos = 0;
        for (int g = 0; g < HH; ++g) {
            float keyg = keep_s[g] ? conf_s[g] : -INFINITY;
            if (keyg > keyh || (keyg == keyh && g < h)) ++pos;
        }
        float nx = nx_s[h], ny = ny_s[h], nz = nz_s[h];
        float t  = nx * cmx + ny * cmy + nz * cmz + d_s[h];
        float px = cmx - t * nx, py = cmy - t * ny, pz = cmz - t * nz;

        float* o = out + (size_t)(b * HH + pos) * 8;
        if (keep_s[h]) {
            o[0] = nx; o[1] = ny; o[2] = nz;
            o[3] = px; o[4] = py; o[5] = pz;
            o[6] = conf_s[h];
            o[7] = sde_s[h];
        } else {
            for (int c = 0; c < 8; ++c) o[c] = 0.0f;
        }
    }
}

extern "C" void kernel_launch(void* const* d_in, const int* in_sizes, int n_in,
                              void* d_out, int out_size, void* d_ws, size_t ws_size,
                              hipStream_t stream) {
    const float* y_pred = (const float*)d_in[0];   // (8,16,4) f32
    const float* sp     = (const float*)d_in[1];   // (8,1024,3) f32
    float* out          = (float*)d_out;           // (8,16,8) f32
    float* ws           = (float*)d_ws;            // 512 floats of block sums

    chamfer_kernel<<<dim3(BB * HH * 4), dim3(TB), 0, stream>>>(y_pred, sp, ws);
    finalize_kernel<<<dim3(BB), dim3(TB), 0, stream>>>(ws, y_pred, sp, out);
}